// Round 15
// baseline (61.576 us; speedup 1.0000x reference)
//
#include <hip/hip_runtime.h>
#include <stdint.h>

// FMFMNeuron LIF scan, 4-phase — occupancy-matched split:
//  1) compress: 134MB f32 spikes -> 4MB 2-bit cur-codes [T/16][B] (nt loads)
//  2) scanA: C=16 chunks x B neurons (1 wave/SIMD, serial chains); 768-step
//     warmup from mem=0 (chunks 0..2 clamped => exact), 256-step body emits
//     1-bit spikes (2MB). 8-word rotating prefetch (distance 128 steps).
//  3) scanB: chain chunks via bit-compare of true state vs spec start;
//     mismatch -> recompute chunk exactly + patch bits. Unconditionally exact.
//  4) expand: 2MB bits -> 67MB f32 at FULL occupancy.
//     GRID = 2048 blocks (4 threads per 32-row word; r14 bug: had 512).
//
// Step math (absmax=0 rounds 1..13): spikes in {0,1} =>
//   cur in {0, w1, w2, fadd(w1,w2)} exactly; strict left-to-right:
//   m = fsub(fadd(fmul(0.95f,mem), cur), rst); spk = m>1.0f; rst' = spk.

#define T_STEPS 4096
#define B_NEUR  4096
#define NCHUNK  16
#define CH_W    16                     // code words per chunk body (256 steps)
#define WARM_W  48                     // warmup words (768 steps)
#define KG      (T_STEPS / 16)         // 256 code words per neuron
#define NWORDS  (T_STEPS / 32)         // 128 spike bit-words per neuron

typedef float f4v __attribute__((ext_vector_type(4)));

// ---- phase 1: compress spikes to 2-bit codes (nt float4 loads) -------------
__global__ __launch_bounds__(256) void fmfm_compress(
    const f4v*  __restrict__ sp4,      // [T][B/2] float4
    uint32_t*   __restrict__ codes)    // [T/16][B]
{
    const int tid = blockIdx.x * 256 + threadIdx.x;   // 0 .. 512K-1
    const int b2  = tid & (B_NEUR / 2 - 1);
    const int kg  = tid >> 11;                        // 0..255
    const f4v* p = sp4 + (size_t)kg * 16 * (B_NEUR / 2) + b2;
    uint32_t we = 0, wo = 0;
    #pragma unroll
    for (int i = 0; i < 16; ++i) {
        f4v s = __builtin_nontemporal_load(p + (size_t)i * (B_NEUR / 2));
        uint32_t ce = (s.x != 0.0f ? 1u : 0u) | (s.y != 0.0f ? 2u : 0u);
        uint32_t co = (s.z != 0.0f ? 1u : 0u) | (s.w != 0.0f ? 2u : 0u);
        we |= ce << (2 * i);
        wo |= co << (2 * i);
    }
    *reinterpret_cast<uint2*>(codes + (size_t)kg * B_NEUR + 2 * b2) =
        make_uint2(we, wo);
}

// ---- phase 2: speculative chunk scan -> spike bits -------------------------
__global__ __launch_bounds__(256) void fmfm_scanA(
    const uint32_t* __restrict__ codes,    // [T/16][B]
    const float*    __restrict__ W,
    uint32_t*       __restrict__ bits_out, // [T/32][B]
    uint4*          __restrict__ spec)     // [C][B]
{
    __shared__ float2 lut2[16];

    const float w1  = W[0];
    const float w2  = W[1];
    const float w12 = __fadd_rn(w1, w2);

    if (threadIdx.x < 16) {
        uint32_t e = threadIdx.x;
        uint32_t c0 = e & 3u, c1 = (e >> 2) & 3u;
        float2 v;
        v.x = (c0 & 1u) ? ((c0 & 2u) ? w12 : w1) : ((c0 & 2u) ? w2 : 0.0f);
        v.y = (c1 & 1u) ? ((c1 & 2u) ? w12 : w1) : ((c1 & 2u) ? w2 : 0.0f);
        lut2[e] = v;
    }
    __syncthreads();

    const int tid = blockIdx.x * 256 + threadIdx.x;   // 0..65535
    const int b   = tid & (B_NEUR - 1);
    const int c   = tid >> 12;                        // chunk 0..15
    const int body_w0 = c * CH_W;
    const int w_start = (body_w0 >= WARM_W) ? body_w0 - WARM_W : 0;
    const int w_end   = body_w0 + CH_W;               // exclusive
    const uint32_t* cp = codes + b;

#define CLD(IDX) cp[(size_t)((IDX) < w_end ? (IDX) : (w_end - 1)) * B_NEUR]
#define DECODE2(WORD, D)                                                  \
    {                                                                     \
        _Pragma("unroll")                                                 \
        for (int _j = 0; _j < 8; ++_j)                                    \
            D[_j] = lut2[((WORD) >> (4 * _j)) & 0xFu];                    \
    }
#define STEPN(CUR)                                                        \
    {                                                                     \
        float _m = __fsub_rn(__fadd_rn(__fmul_rn(0.95f, mem), (CUR)),     \
                             rst);                                        \
        rst = (_m > 1.0f) ? 1.0f : 0.0f;                                  \
        mem = _m;                                                         \
    }
#define STEPB(CUR, POS)                                                   \
    {                                                                     \
        float _m = __fsub_rn(__fadd_rn(__fmul_rn(0.95f, mem), (CUR)),     \
                             rst);                                        \
        uint32_t _sb = (_m > 1.0f) ? 1u : 0u;                             \
        bits |= _sb << (POS);                                             \
        rst = _sb ? 1.0f : 0.0f;                                          \
        mem = _m;                                                         \
    }
#define CHAIN16N(D)                                                       \
    {                                                                     \
        _Pragma("unroll")                                                 \
        for (int _j = 0; _j < 8; ++_j) { STEPN(D[_j].x) STEPN(D[_j].y) }  \
    }
#define CHAIN16B(D, HALF)                                                 \
    {                                                                     \
        _Pragma("unroll")                                                 \
        for (int _j = 0; _j < 8; ++_j) {                                  \
            STEPB(D[_j].x, ((HALF) << 4) + 2 * _j)                        \
            STEPB(D[_j].y, ((HALF) << 4) + 2 * _j + 1)                    \
        }                                                                 \
    }
#define PF8(G)                                                            \
    t0 = CLD((G) + 8);  t1 = CLD((G) + 9);  t2 = CLD((G) + 10);           \
    t3 = CLD((G) + 11); t4 = CLD((G) + 12); t5 = CLD((G) + 13);           \
    t6 = CLD((G) + 14); t7 = CLD((G) + 15);
#define ROT8()                                                            \
    c0 = t0; c1 = t1; c2 = t2; c3 = t3;                                   \
    c4 = t4; c5 = t5; c6 = t6; c7 = t7;
#define STB(IDX) bits_out[(size_t)(IDX) * B_NEUR + b] = bits;

    uint32_t c0 = CLD(w_start);     uint32_t c1 = CLD(w_start + 1);
    uint32_t c2 = CLD(w_start + 2); uint32_t c3 = CLD(w_start + 3);
    uint32_t c4 = CLD(w_start + 4); uint32_t c5 = CLD(w_start + 5);
    uint32_t c6 = CLD(w_start + 6); uint32_t c7 = CLD(w_start + 7);
    uint32_t t0, t1, t2, t3, t4, t5, t6, t7;

    float2 dA[8], dB[8];
    DECODE2(c0, dA)

    float mem = 0.0f, rst = 0.0f;

    // warmup groups (8 words = 128 steps each); trip 0 for chunk 0
    for (int g = w_start; g < body_w0; g += 8) {
        PF8(g)
        DECODE2(c1, dB) CHAIN16N(dA)
        DECODE2(c2, dA) CHAIN16N(dB)
        DECODE2(c3, dB) CHAIN16N(dA)
        DECODE2(c4, dA) CHAIN16N(dB)
        DECODE2(c5, dB) CHAIN16N(dA)
        DECODE2(c6, dA) CHAIN16N(dB)
        DECODE2(c7, dB) CHAIN16N(dA)
        DECODE2(t0, dA) CHAIN16N(dB)
        ROT8()
    }

    const float sm = mem;
    const float sr = rst;

    // body groups (2 x 8 words), emitting spike bit-words
    for (int g = body_w0; g < w_end; g += 8) {
        PF8(g)
        uint32_t bits = 0;
        DECODE2(c1, dB) CHAIN16B(dA, 0)
        DECODE2(c2, dA) CHAIN16B(dB, 1) STB((g + 1) >> 1) bits = 0;
        DECODE2(c3, dB) CHAIN16B(dA, 0)
        DECODE2(c4, dA) CHAIN16B(dB, 1) STB((g + 3) >> 1) bits = 0;
        DECODE2(c5, dB) CHAIN16B(dA, 0)
        DECODE2(c6, dA) CHAIN16B(dB, 1) STB((g + 5) >> 1) bits = 0;
        DECODE2(c7, dB) CHAIN16B(dA, 0)
        DECODE2(t0, dA) CHAIN16B(dB, 1) STB((g + 7) >> 1)
        ROT8()
    }

    uint4 sv;
    sv.x = __float_as_uint(sm);
    sv.y = (sr != 0.0f) ? 1u : 0u;
    sv.z = __float_as_uint(mem);
    sv.w = (rst != 0.0f) ? 1u : 0u;
    spec[(size_t)c * B_NEUR + b] = sv;

#undef CLD
#undef DECODE2
#undef STEPN
#undef STEPB
#undef CHAIN16N
#undef CHAIN16B
#undef PF8
#undef ROT8
#undef STB
}

// ---- phase 3: exact chaining / verification, patches bits ------------------
__global__ __launch_bounds__(64) void fmfm_scanB(
    const uint32_t* __restrict__ codes,
    const float*    __restrict__ W,
    uint32_t*       __restrict__ bits_out,
    const uint4*    __restrict__ spec)
{
    const int b = blockIdx.x * 64 + threadIdx.x;
    const float w1  = W[0];
    const float w2  = W[1];
    const float w12 = __fadd_rn(w1, w2);

    float mem = 0.0f, rst = 0.0f;
    uint4 sn = spec[b];
    for (int c = 0; c < NCHUNK; ++c) {
        uint4 s = sn;
        if (c + 1 < NCHUNK) sn = spec[(size_t)(c + 1) * B_NEUR + b];
        bool ok = (s.x == __float_as_uint(mem)) &&
                  ((s.y != 0u) == (rst != 0.0f));
        if (ok) {
            mem = __uint_as_float(s.z);
            rst = s.w ? 1.0f : 0.0f;
        } else {
            // rare: recompute chunk c exactly from true state, patch bits
            uint32_t bits = 0;
            for (int wi = 0; wi < CH_W; ++wi) {
                uint32_t w = codes[(size_t)(c * CH_W + wi) * B_NEUR + b];
                #pragma unroll
                for (int j = 0; j < 16; ++j) {
                    uint32_t cc = (w >> (2 * j)) & 3u;
                    float cur = (cc & 1u) ? ((cc & 2u) ? w12 : w1)
                                          : ((cc & 2u) ? w2 : 0.0f);
                    float m = __fsub_rn(__fadd_rn(__fmul_rn(0.95f, mem), cur),
                                        rst);
                    uint32_t sb = (m > 1.0f) ? 1u : 0u;
                    bits |= sb << (((wi & 1) << 4) + j);
                    rst = sb ? 1.0f : 0.0f;
                    mem = m;
                }
                if (wi & 1) {
                    bits_out[(size_t)((c * CH_W + wi) >> 1) * B_NEUR + b] = bits;
                    bits = 0;
                }
            }
        }
    }
}

// ---- phase 4: expand bits -> f32, full occupancy ---------------------------
__global__ __launch_bounds__(256) void fmfm_expand(
    const uint32_t* __restrict__ bits,  // [T/32][B]
    float*          __restrict__ out)   // [T][B]
{
    const int tid = blockIdx.x * 256 + threadIdx.x;  // 0..524287
    const int b4  = tid & 1023;                      // neuron quad
    const int w   = (tid >> 10) & 127;               // bit-word row
    const int q   = tid >> 17;                       // row octet 0..3
    const uint4 bw = *reinterpret_cast<const uint4*>(
        bits + (size_t)w * B_NEUR + (size_t)b4 * 4);
    float* qp = out + ((size_t)w * 32 + q * 8) * B_NEUR + (size_t)b4 * 4;
    #pragma unroll
    for (int r = 0; r < 8; ++r) {
        const int tp = q * 8 + r;
        f4v v;
        v.x = ((bw.x >> tp) & 1u) ? 1.0f : 0.0f;
        v.y = ((bw.y >> tp) & 1u) ? 1.0f : 0.0f;
        v.z = ((bw.z >> tp) & 1u) ? 1.0f : 0.0f;
        v.w = ((bw.w >> tp) & 1u) ? 1.0f : 0.0f;
        *reinterpret_cast<f4v*>(qp + (size_t)r * B_NEUR) = v;
    }
}

// ---- fallback: round-1 proven fused kernel (if ws too small) ---------------
__global__ __launch_bounds__(64) void fmfm_scan_fused(
    const float2* __restrict__ sp, const float* __restrict__ W,
    float* __restrict__ out)
{
    const int b = blockIdx.x * 64 + threadIdx.x;
    const float w1 = W[0];
    const float w2 = W[1];
    const float2* p = sp + b;
    float* q = out + b;
    float mem = 0.0f, rst = 0.0f;
    #pragma unroll 8
    for (int t = 0; t < T_STEPS; ++t) {
        float2 s = p[(size_t)t * B_NEUR];
        float cur = __fadd_rn(__fmul_rn(s.x, w1), __fmul_rn(s.y, w2));
        float m = __fsub_rn(__fadd_rn(__fmul_rn(0.95f, mem), cur), rst);
        float spk = (m > 1.0f) ? 1.0f : 0.0f;
        q[(size_t)t * B_NEUR] = spk;
        mem = m;
        rst = spk;
    }
}

extern "C" void kernel_launch(void* const* d_in, const int* in_sizes, int n_in,
                              void* d_out, int out_size, void* d_ws, size_t ws_size,
                              hipStream_t stream) {
    const f4v*   sp4 = (const f4v*)d_in[0];
    const float* W   = (const float*)d_in[1];
    float*       out = (float*)d_out;

    const size_t codes_bytes = (size_t)KG * B_NEUR * 4;          // 4MB
    const size_t bits_bytes  = (size_t)NWORDS * B_NEUR * 4;      // 2MB
    const size_t spec_bytes  = (size_t)NCHUNK * B_NEUR * 16;     // 1MB
    if (ws_size < codes_bytes + bits_bytes + spec_bytes) {
        fmfm_scan_fused<<<dim3(B_NEUR / 64), dim3(64), 0, stream>>>(
            (const float2*)d_in[0], W, out);
        return;
    }
    uint32_t* codes = (uint32_t*)d_ws;
    uint32_t* bits  = (uint32_t*)((char*)d_ws + codes_bytes);
    uint4*    spec  = (uint4*)((char*)d_ws + codes_bytes + bits_bytes);

    fmfm_compress<<<dim3(KG * (B_NEUR / 2) / 256), dim3(256), 0, stream>>>(sp4, codes);
    fmfm_scanA<<<dim3(NCHUNK * B_NEUR / 256), dim3(256), 0, stream>>>(codes, W, bits, spec);
    fmfm_scanB<<<dim3(B_NEUR / 64), dim3(64), 0, stream>>>(codes, W, bits, spec);
    // 4 threads per 32-row bit-word: 128 * 1024 * 4 / 256 = 2048 blocks
    fmfm_expand<<<dim3(NWORDS * (B_NEUR / 4) * 4 / 256), dim3(256), 0, stream>>>(bits, out);
}